// Round 8
// baseline (137.294 us; speedup 1.0000x reference)
//
#include <hip/hip_runtime.h>
#include <hip/hip_bf16.h>

// Problem: B=2, S=2048, D=256, H=8.
// out[b,h,s,:] = sum_{t<=s} exp( max(d2(s,t),0) / (2*gamma_h - 1e-6) ) * V[b,t,:]
// d2(s,t) = |Q_s|^2 + |K_t|^2 - 2 Q_s.K_t ; Q=p@Wq, K=p@Wk, V=e@Wv.
// Heads with equal gamma produce identical outputs -> dedupe by representative.
//
// R7: fragment-major operands (1KB contiguous b128 runs).  R8: repack fused
// into GEMM epilogue; split partials + reduce (136us).  R9: TSPLIT=8 regressed
// (traffic duplication).  R10: fence-fused reduction regressed badly.
// R11: dual-tile flash ILP: 131.8us.  R12/R13: regressions, reverted.
// R14: gemm bounds(256,3) + XCD-local p/e decode: 128.0us (best).
// R15: flash occupancy 2x at ZERO traffic cost: split each triangle-pair's
// two halves into separate blocks (grid 256->512, 2 blocks/CU, 2 waves/SIMD).
// Q/K/V/partial traffic byte-identical; consecutive bids alternate short/long
// jobs so CU-resident pairs stay balanced.

#define BB   2
#define SS   2048
#define DD   256
#define HH   8
#define BSR  (BB*SS)        // 4096 rows
#define TSPLIT 4

typedef __bf16 bf16_t;
typedef __bf16 bf16x8 __attribute__((ext_vector_type(8)));
typedef float  f32x4  __attribute__((ext_vector_type(4)));

static __device__ __forceinline__ f32x4 mfma16(bf16x8 a, bf16x8 b, f32x4 c) {
    return __builtin_amdgcn_mfma_f32_16x16x32_bf16(a, b, c, 0, 0, 0);
}

// ---------------------------------------------------------------------------
// K0: W -> fragment-major WF (hi/lo split), plus q2/k2 zeroing (block 48).
// WF chunk (g16 in [0,16), kc in [0,8)) holds 512 elems at ((g16*8+kc)*512):
// position u*8+j = W^T[n = g16*16 + (u&15)][k = kc*32 + (u>>4)*8 + j].
// gemm's B-frag load is then base + lane*8 : contiguous 1KB per wave.
// ---------------------------------------------------------------------------
__global__ __launch_bounds__(256) void att_wtrans(
    const float* __restrict__ Wq, const float* __restrict__ Wk,
    const float* __restrict__ Wv,
    bf16_t* __restrict__ WFq_h, bf16_t* __restrict__ WFq_l,
    bf16_t* __restrict__ WFk_h, bf16_t* __restrict__ WFk_l,
    bf16_t* __restrict__ WFv, float* __restrict__ q2, float* __restrict__ k2)
{
    __shared__ float tT[64][68];    // [n_local][k_local], pad 68
    const int tid = threadIdx.x;
    if (blockIdx.x == 48) {         // zero q2/k2 (gemm accumulates atomically)
        for (int i = tid; i < BSR; i += 256) { q2[i] = 0.f; k2[i] = 0.f; }
        return;
    }
    const int mat = blockIdx.x >> 4;        // 0=Wq 1=Wk 2=Wv
    const int tl  = blockIdx.x & 15;
    const int tr  = (tl >> 2) * 64, tc = (tl & 3) * 64;  // k-range, n-range
    const float* W = (mat == 0) ? Wq : ((mat == 1) ? Wk : Wv);

    // load W[k][n] tile rows coalesced, scatter transposed into LDS
#pragma unroll
    for (int i = 0; i < 4; ++i) {
        const int fidx = i * 256 + tid;     // [0,1024) float4 units
        const int r  = fidx >> 4;           // k_local
        const int c4 = fidx & 15;           // n_local/4
        const float4 v = *(const float4*)(W + (size_t)(tr + r) * DD + tc + c4 * 4);
        tT[c4 * 4 + 0][r] = v.x; tT[c4 * 4 + 1][r] = v.y;
        tT[c4 * 4 + 2][r] = v.z; tT[c4 * 4 + 3][r] = v.w;
    }
    __syncthreads();

#pragma unroll
    for (int i = 0; i < 2; ++i) {
        const int uidx  = i * 256 + tid;    // [0,512) 16B units
        const int chunk = uidx >> 6;        // kc_l(2) x c16(4)
        const int kc_l  = chunk >> 2, c16 = chunk & 3;
        const int u = uidx & 63, m16 = u & 15, quad = u >> 4;
        const float* src = &tT[c16 * 16 + m16][kc_l * 32 + quad * 8];
        const float4 a = *(const float4*)src;
        const float4 bq = *(const float4*)(src + 4);
        const float f[8] = {a.x, a.y, a.z, a.w, bq.x, bq.y, bq.z, bq.w};
        bf16x8 hi, lo;
#pragma unroll
        for (int j = 0; j < 8; ++j) {
            const bf16_t h = (bf16_t)f[j];
            hi[j] = h; lo[j] = (bf16_t)(f[j] - (float)h);
        }
        const int g16 = (tc >> 4) + c16;
        const int kcg = (tr >> 5) + kc_l;
        const size_t off = ((size_t)(g16 * 8 + kcg)) * 512 + (size_t)u * 8;
        if (mat == 0)      { *(bf16x8*)(WFq_h + off) = hi; *(bf16x8*)(WFq_l + off) = lo; }
        else if (mat == 1) { *(bf16x8*)(WFk_h + off) = hi; *(bf16x8*)(WFk_l + off) = lo; }
        else               { *(bf16x8*)(WFv + off)  = hi; }
    }
}

// ---------------------------------------------------------------------------
// K1: fused QKV projection via MFMA + DIRECT fragment-major epilogue.
// Block = 256 thr, 16 rows x 64 n-cols.  R14: bounds(256,3) for 3 blocks/CU
// TLP; bijective XCD-local decode: xcd=bid&7, j=bid>>3, nb=j>>5,
// rowslice=xcd*32+(j&31) -> all 4 nb-jobs of a row-slice share one XCD's L2.
// ---------------------------------------------------------------------------
__global__ __launch_bounds__(256, 3) void att_gemm_qkv(
    const float* __restrict__ p, const float* __restrict__ e,
    const bf16_t* __restrict__ WFq_h, const bf16_t* __restrict__ WFq_l,
    const bf16_t* __restrict__ WFk_h, const bf16_t* __restrict__ WFk_l,
    const bf16_t* __restrict__ WFv,
    bf16_t* __restrict__ QFh, bf16_t* __restrict__ QFl,
    bf16_t* __restrict__ KFh, bf16_t* __restrict__ KFl,
    bf16_t* __restrict__ VF, float* __restrict__ q2, float* __restrict__ k2)
{
    __shared__ float pL[16][264];
    __shared__ float eL[16][264];
    __shared__ float fQ[16][68];
    __shared__ float fK[16][68];
    __shared__ float fV[16][68];

    const int tid  = threadIdx.x;
    const int w    = tid >> 6;
    const int lane = tid & 63;
    const int m16  = lane & 15;
    const int quad = lane >> 4;
    const int xcd  = blockIdx.x & 7;
    const int jid  = blockIdx.x >> 3;      // [0,128)
    const int nb   = jid >> 5;             // [0,4)
    const int row0 = (xcd * 32 + (jid & 31)) * 16;

    // stage p/e tiles (16 rows x 256 cols), coalesced
#pragma unroll
    for (int i = 0; i < 4; ++i) {
        const int fidx = i * 256 + tid;     // [0,1024) float4
        const int r  = fidx >> 6;
        const int c4 = fidx & 63;
        const float4 pv = *(const float4*)(p + (size_t)(row0 + r) * DD + c4 * 4);
        const float4 ev = *(const float4*)(e + (size_t)(row0 + r) * DD + c4 * 4);
        *(float4*)&pL[r][c4 * 4] = pv;
        *(float4*)&eL[r][c4 * 4] = ev;
    }
    __syncthreads();

    f32x4 aQ = f32x4{0.f, 0.f, 0.f, 0.f};
    f32x4 aK = f32x4{0.f, 0.f, 0.f, 0.f};
    f32x4 aV = f32x4{0.f, 0.f, 0.f, 0.f};

#pragma unroll 2
    for (int kc = 0; kc < 8; ++kc) {
        const float* ps = &pL[m16][kc * 32 + quad * 8];
        const float* es = &eL[m16][kc * 32 + quad * 8];
        const float4 p0 = *(const float4*)ps;
        const float4 p1 = *(const float4*)(ps + 4);
        const float4 e0 = *(const float4*)es;
        const float4 e1 = *(const float4*)(es + 4);
        const float pa[8] = {p0.x, p0.y, p0.z, p0.w, p1.x, p1.y, p1.z, p1.w};
        const float ea[8] = {e0.x, e0.y, e0.z, e0.w, e1.x, e1.y, e1.z, e1.w};
        bf16x8 aph, apl, aeb;
#pragma unroll
        for (int j = 0; j < 8; ++j) {
            const bf16_t h = (bf16_t)pa[j];
            aph[j] = h;
            apl[j] = (bf16_t)(pa[j] - (float)h);
            aeb[j] = (bf16_t)ea[j];
        }
        const size_t wo = ((size_t)((nb * 4 + w) * 8 + kc)) * 512 + (size_t)lane * 8;
        const bf16x8 bqh = *(const bf16x8*)(WFq_h + wo);
        const bf16x8 bql = *(const bf16x8*)(WFq_l + wo);
        const bf16x8 bkh = *(const bf16x8*)(WFk_h + wo);
        const bf16x8 bkl = *(const bf16x8*)(WFk_l + wo);
        const bf16x8 bv  = *(const bf16x8*)(WFv + wo);
        aQ = mfma16(aph, bqh, aQ);
        aQ = mfma16(apl, bqh, aQ);
        aQ = mfma16(aph, bql, aQ);
        aK = mfma16(aph, bkh, aK);
        aK = mfma16(apl, bkh, aK);
        aK = mfma16(aph, bkl, aK);
        aV = mfma16(aeb, bv, aV);
    }

    // stage accumulators f32 into LDS for the fragment transpose
#pragma unroll
    for (int r = 0; r < 4; ++r) {
        const int rl = quad * 4 + r;          // C/D row = quad*4+reg
        fQ[rl][w * 16 + m16] = aQ[r];
        fK[rl][w * 16 + m16] = aK[r];
        fV[rl][w * 16 + m16] = aV[r];
    }

    // q2/k2 row-norm partials (from f32 accumulators)
#pragma unroll
    for (int r = 0; r < 4; ++r) {
        float vq = aQ[r] * aQ[r], vk = aK[r] * aK[r];
#pragma unroll
        for (int off = 8; off >= 1; off >>= 1) {
            vq += __shfl_xor(vq, off);
            vk += __shfl_xor(vk, off);
        }
        if (m16 == 0) {
            atomicAdd(q2 + row0 + quad * 4 + r, vq);
            atomicAdd(k2 + row0 + quad * 4 + r, vk);
        }
    }

    __syncthreads();

    const int b   = row0 >> 11;
    const int sl  = row0 & 2047;
    const int tt  = sl >> 6;
    const int st  = sl >> 5;
    const int w4  = (sl >> 4) & 3;   // KF row-group
    const int mt  = (sl >> 4) & 1;   // QF row-group
    const int kc2 = (sl >> 5) & 1;   // VF t-half
    const int uh  = (sl >> 4) & 1;   // VF u-half

    if (w < 2) {
        // QF chunk kc = nb*2 + w  (hi + lo)
        const int cl = w;
        const float* src = &fQ[m16][cl * 32 + quad * 8];
        const float4 a = *(const float4*)src;
        const float4 c = *(const float4*)(src + 4);
        const float f[8] = {a.x, a.y, a.z, a.w, c.x, c.y, c.z, c.w};
        bf16x8 hi, lo;
#pragma unroll
        for (int j = 0; j < 8; ++j) {
            const bf16_t h = (bf16_t)f[j];
            hi[j] = h; lo[j] = (bf16_t)(f[j] - (float)h);
        }
        const size_t off = ((size_t)(b * 64 + st)) * 8192
                         + (size_t)(mt * 8 + nb * 2 + cl) * 512 + (size_t)lane * 8;
        *(bf16x8*)(QFh + off) = hi; *(bf16x8*)(QFl + off) = lo;
    } else {
        // KF chunk kc = nb*2 + (w-2)  (hi + lo)
        const int cl = w - 2;
        const float* src = &fK[m16][cl * 32 + quad * 8];
        const float4 a = *(const float4*)src;
        const float4 c = *(const float4*)(src + 4);
        const float f[8] = {a.x, a.y, a.z, a.w, c.x, c.y, c.z, c.w};
        bf16x8 hi, lo;
#pragma unroll
        for (int j = 0; j < 8; ++j) {
            const bf16_t h = (bf16_t)f[j];
            hi[j] = h; lo[j] = (bf16_t)(f[j] - (float)h);
        }
        const size_t off = ((size_t)(b * 32 + tt)) * 16384
                         + (size_t)(w4 * 8 + nb * 2 + cl) * 512 + (size_t)lane * 8;
        *(bf16x8*)(KFh + off) = hi; *(bf16x8*)(KFl + off) = lo;
    }

    // VF half-chunks: wave w handles nt=w with lanes 0..31 (u-half uh)
    if (lane < 32) {
        const int nt  = w;
        const int u   = uh * 32 + lane;
        const int tl0 = (lane >> 4) * 8;     // t_local base within block rows
        bf16x8 vb;
#pragma unroll
        for (int j = 0; j < 8; ++j)
            vb[j] = (bf16_t)fV[tl0 + j][nt * 16 + (lane & 15)];
        const size_t off = ((size_t)(b * 32 + tt)) * 16384
                         + (size_t)(nb * 8 + kc2 * 4 + nt) * 512 + (size_t)u * 8;
        *(bf16x8*)(VF + off) = vb;
    }
}

// ---------------------------------------------------------------------------
// K2: flash-style causal pass, fragment-major operands.
// R15: halves split into the grid -> 512 blocks (32 pairs x 2 halves x 8 sub)
// = 2 blocks/CU = 2 waves/SIMD, with byte-identical traffic to the paired
// version (each (b,st,split) loads Q/K/V and stores partials exactly once).
// bid&7 == split*2+b keeps one (split,b) class per XCD (K/V set fits L2).
// Consecutive bids alternate st=pair (short) / st=63-pair (long) -> CU-
// resident block pairs stay balanced.  Dual-tile inner loop as R11.
// ---------------------------------------------------------------------------
__global__ __launch_bounds__(256, 2) void att_flash(
    const bf16_t* __restrict__ QFh, const bf16_t* __restrict__ QFl,
    const bf16_t* __restrict__ KFh, const bf16_t* __restrict__ KFl,
    const bf16_t* __restrict__ VF, const float* __restrict__ q2,
    const float* __restrict__ k2, const float* __restrict__ gamma,
    float* __restrict__ part, float* __restrict__ out)
{
    __shared__ bf16_t Pb[2][2][32][72];   // [parity][tile-in-pair][s][t]

    const int tid   = threadIdx.x;
    const int sub   = blockIdx.x & 7;      // == xcd class
    const int split = sub >> 1;            // 0..3
    const int b     = sub & 1;
    const int j     = blockIdx.x >> 3;     // 0..63
    const int pair  = j >> 1;              // 0..31
    const int half  = j & 1;
    const int st    = half ? (63 - pair) : pair;
    const int wave  = tid >> 6;
    const int lane  = tid & 63;
    const int m16   = lane & 15;
    const int quad  = lane >> 4;

    float g[8];
#pragma unroll
    for (int h = 0; h < 8; ++h) g[h] = gamma[h];

    int q = 0;

    const int s0 = st * 32;

    // Q fragments -> registers, contiguous chunk loads.
    bf16x8 aQh[2][8], aQl[2][8];
    const size_t qtile = ((size_t)(b * 64 + st)) * 8192 + (size_t)lane * 8;
#pragma unroll
    for (int mt = 0; mt < 2; ++mt)
#pragma unroll
        for (int kc = 0; kc < 8; ++kc) {
            const size_t base = qtile + (size_t)(mt * 8 + kc) * 512;
            aQh[mt][kc] = *(const bf16x8*)(QFh + base);
            aQl[mt][kc] = *(const bf16x8*)(QFl + base);
        }

    float q2r[2][4];
#pragma unroll
    for (int mt = 0; mt < 2; ++mt)
#pragma unroll
        for (int r = 0; r < 4; ++r)
            q2r[mt][r] = q2[b * SS + s0 + mt * 16 + quad * 4 + r];

    const int n_tiles = (s0 + 31) / 64 + 1;

    for (int h = 0; h < HH; ++h) {
        int rep = 0;
        while (g[rep] != g[h]) ++rep;
        if (rep != h) continue;
        const float cexp = 1.0f / (2.0f * g[h] - 1e-6f);

        f32x4 O[2][4];
#pragma unroll
        for (int mt = 0; mt < 2; ++mt)
#pragma unroll
            for (int nt = 0; nt < 4; ++nt)
                O[mt][nt] = f32x4{0.f, 0.f, 0.f, 0.f};

        int ti = split;

        // ---- dual-tile iterations: tiles ti and ti+TSPLIT together ----
        while (ti + TSPLIT < n_tiles) {
            const int tiA = ti, tiB = ti + TSPLIT;
            const int tgA = tiA * 64 + wave * 16 + m16;
            const int tgB = tiB * 64 + wave * 16 + m16;
            const size_t tileA = ((size_t)(b * 32 + tiA)) * 16384
                               + (size_t)wave * 4096 + (size_t)lane * 8;
            const size_t tileB = ((size_t)(b * 32 + tiB)) * 16384
                               + (size_t)wave * 4096 + (size_t)lane * 8;

            // V prefetch for both tiles (overlaps scores + barrier)
            bf16x8 vfA[2][4], vfB[2][4];
#pragma unroll
            for (int kc2 = 0; kc2 < 2; ++kc2)
#pragma unroll
                for (int nt = 0; nt < 4; ++nt) {
                    vfA[kc2][nt] = *(const bf16x8*)(
                        VF + tileA + (size_t)(kc2 * 4 + nt) * 512);
                    vfB[kc2][nt] = *(const bf16x8*)(
                        VF + tileB + (size_t)(kc2 * 4 + nt) * 512);
                }
            const float k2A = k2[b * SS + tgA];
            const float k2B = k2[b * SS + tgB];

            // scores: 4 independent accumulator chains (2 tiles x 2 mt)
            f32x4 aA0 = f32x4{0.f, 0.f, 0.f, 0.f};
            f32x4 aA1 = f32x4{0.f, 0.f, 0.f, 0.f};
            f32x4 aB0 = f32x4{0.f, 0.f, 0.f, 0.f};
            f32x4 aB1 = f32x4{0.f, 0.f, 0.f, 0.f};
#pragma unroll
            for (int kc = 0; kc < 8; ++kc) {
                const bf16x8 bhA = *(const bf16x8*)(KFh + tileA + (size_t)kc * 512);
                const bf16x8 blA = *(const bf16x8*)(KFl + tileA + (size_t)kc * 512);
                const bf16x8 bhB = *(const bf16x8*)(KFh + tileB + (size_t)kc * 512);
                const bf16x8 blB = *(const bf16x8*)(KFl + tileB + (size_t)kc * 512);
                aA0 = mfma16(aQh[0][kc], bhA, aA0);
                aA1 = mfma16(aQh[1][kc], bhA, aA1);
                aB0 = mfma16(aQh[0][kc], bhB, aB0);
                aB1 = mfma16(aQh[1][kc], bhB, aB1);
                aA0 = mfma16(aQl[0][kc], bhA, aA0);
                aA1 = mfma16(aQl[1][kc], bhA, aA1);
                aB0 = mfma16(aQl[0][kc], bhB, aB0);
                aB1 = mfma16(aQl[1][kc], bhB, aB1);
                aA0 = mfma16(aQh[0][kc], blA, aA0);
                aA1 = mfma16(aQh[1][kc], blA, aA1);
                aB0 = mfma16(aQh[0][kc], blB, aB0);
                aB1 = mfma16(aQh[1][kc], blB, aB1);
            }

#pragma unroll
            for (int mt = 0; mt < 2; ++mt) {
#pragma unroll
                for (int r = 0; r < 4; ++r) {
                    const int sl = mt * 16 + quad * 4 + r;
                    const int sg = s0 + sl;
                    float dA = q2r[mt][r] + k2A
                             - 2.0f * (mt ? aA1[r] : aA0[r]);
                    dA = fmaxf(dA, 0.0f);
                    const float wA = (tgA <= sg) ? __expf(cexp * dA) : 0.0f;
                    Pb[q][0][sl][wave * 16 + m16] = (bf16_t)wA;
                    float dB = q2r[mt][r] + k2B
                             - 2.0f * (mt ? aB1[r] : aB0[r]);
                    dB = fmaxf(dB, 0.0f);
                    const float wB = (tgB <= sg) ? __expf(cexp * dB) : 0.0f;
                    Pb[q][1][sl][wave * 16 + m16] = (bf16_t)wB;
                }
            }
            __syncthreads();

            // PV: tile A fully first, then tile B (same add order as R8)
#pragma unroll
            for (int kc2 = 0; kc2 < 2; ++kc2) {
                const bf16x8 pa0 = *(const bf16x8*)&Pb[q][0][m16][kc2 * 32 + quad * 8];
                const bf16x8 pa1 = *(const bf16x8*)&Pb[q][0][m16 + 16][kc2 * 32 + quad * 8];
#pragma unroll
                for (int nt = 0; nt < 4; ++nt) {
                    O[0][nt] = mfma16(pa0, vfA[kc2][nt], O[0][nt]);
                    O[1][nt] = mfma16(pa1, vfA[kc2][nt], O[1][nt]);
                }
            }
#pragma unroll
            for (int kc2 = 0; kc2 < 2; ++kc2) {
                const bf16x8 pb0 = *(const bf16x8*)&Pb[q][1][m16][kc2 * 32 + quad * 8];
                const bf16x8 pb1 = *(const bf16x8*)&Pb[q][1][m16 + 16][kc2 * 32 + quad * 8];
#pragma unroll
                for (int nt = 0; nt < 4; ++nt) {
                    O[0][nt] = mfma16(pb0, vfB[kc2][nt], O[0][nt]);
                    O[1][nt] = mfma16(pb1, vfB[kc2][nt], O[1][nt]);
                }
            }
            q ^= 1;
            ti += 2 * TSPLIT;
        }

        // ---- single-tile tail (at most one) ----
        if (ti < n_tiles) {
            const int tg = ti * 64 + wave * 16 + m16;
            const size_t tile = ((size_t)(b * 32 + ti)) * 16384
                              + (size_t)wave * 4096 + (size_t)lane * 8;

            bf16x8 vf[2][4];
#pragma unroll
            for (int kc2 = 0; kc2 < 2; ++kc2)
#pragma unroll
                for (int nt = 0; nt < 4; ++nt)
                    vf[kc2][nt] = *(const bf16x8*)(
                        VF + tile + (size_t)(kc2 * 4 + nt) * 512);
            const float k2v = k2[b * SS + tg];

            f32x4 acc0 = f32x4{0.f, 0.f, 0.f, 0.f};
            f32x4 acc1 = f32x4{0.f, 0.f, 0.f, 0.f};
#pragma unroll
            for (int kc = 0; kc < 8; ++kc) {
                const bf16x8 bh = *(const bf16x8*)(KFh + tile + (size_t)kc * 512);
                const bf16x8 bl = *(const bf16x8*)(KFl + tile + (size_t)kc * 512);
                acc0 = mfma16(aQh[0][kc], bh, acc0);
                acc1 = mfma16(aQh[1][kc], bh, acc1);
                acc0 = mfma16(aQl[0][kc], bh, acc0);
                acc1 = mfma16(aQl[1][kc], bh, acc1);
                acc0 = mfma16(aQh[0][kc], bl, acc0);
                acc1 = mfma16(aQh[1][kc], bl, acc1);
            }

#pragma unroll
            for (int mt = 0; mt < 2; ++mt) {
#pragma unroll
                for (int r = 0; r < 4; ++r) {
                    const int sl = mt * 16 + quad * 4 + r;
                    const int sg = s0 + sl;
                    const float dotv = mt ? acc1[r] : acc0[r];
                    float d2 = q2r[mt][r] + k2v - 2.0f * dotv;
                    d2 = fmaxf(d2, 0.0f);
                    const float wgt = (tg <= sg) ? __expf(cexp * d2) : 0.0f;
                    Pb[q][0][sl][wave * 16 + m16] = (bf16_t)wgt;
                }
            }
            __syncthreads();

#pragma unroll
            for (int kc2 = 0; kc2 < 2; ++kc2) {
                const bf16x8 pa0 = *(const bf16x8*)&Pb[q][0][m16][kc2 * 32 + quad * 8];
                const bf16x8 pa1 = *(const bf16x8*)&Pb[q][0][m16 + 16][kc2 * 32 + quad * 8];
#pragma unroll
                for (int nt = 0; nt < 4; ++nt) {
                    O[0][nt] = mfma16(pa0, vf[kc2][nt], O[0][nt]);
                    O[1][nt] = mfma16(pa1, vf[kc2][nt], O[1][nt]);
                }
            }
            q ^= 1;
        }

        // plain stores: split0 -> out slab, splits 1..3 -> ws partials
        float* dst = (split == 0)
            ? out  + (((size_t)b * HH + h) * SS + s0) * DD
            : part + ((((size_t)(split - 1) * BB + b) * HH + h) * SS + s0) * DD;
#pragma unroll
        for (int mt = 0; mt < 2; ++mt)
#pragma unroll
            for (int nt = 0; nt < 4; ++nt)
#pragma unroll
                for (int r = 0; r < 4; ++r)
                    dst[(size_t)(mt * 16 + quad * 4 + r) * DD
                        + wave * 64 + nt * 16 + m16] = O[mt][nt][r];
    }
}

// ---------------------------------------------------------------------------
// K3: reduce split partials into rep heads and broadcast to duplicate-gamma
// heads.  out[b][rep] already holds split0; add 3 partial slabs, write to
// every head sharing that gamma.
// ---------------------------------------------------------------------------
__global__ __launch_bounds__(256) void att_reduce_bcast(
    const float* __restrict__ gamma, const float* __restrict__ part,
    float* __restrict__ out)
{
    const int j = blockIdx.x * 256 + threadIdx.x;   // float4 index within slab
    const int b = blockIdx.y;
    const int slab = SS * DD / 4;

    float g[8];
#pragma unroll
    for (int h = 0; h < 8; ++h) g[h] = gamma[h];

    const float4* pp = (const float4*)part;
    float4* o4 = (float4*)out;

    float4 repval{0.f, 0.f, 0.f, 0.f};
    int last_rep = -1;
#pragma unroll
    for (int h = 0; h < HH; ++h) {
        int rep = 0;
        while (g[rep] != g[h]) ++rep;
        float4* o = o4 + ((size_t)(b * HH + h)) * slab + j;
        if (rep == h) {
            float4 v = *o;
#pragma unroll
            for (int k = 0; k < TSPLIT - 1; ++k) {
                const float4 pv = pp[(((size_t)k * BB + b) * HH + h) * slab + j];
                v.x += pv.x; v.y += pv.y; v.z += pv.z; v.w += pv.w;
            }
            *o = v; repval = v; last_rep = h;
        } else {
            if (last_rep != rep) {
                repval = o4[((size_t)(b * HH + rep)) * slab + j];
                last_rep = rep;
            }
            *o = repval;
        }
    }
}

extern "C" void kernel_launch(void* const* d_in, const int* in_sizes, int n_in,
                              void* d_out, int out_size, void* d_ws, size_t ws_size,
                              hipStream_t stream) {
    (void)in_sizes; (void)n_in; (void)out_size; (void)ws_size;
    // inputs: 0=x (unused), 1=e, 2=p, 3=W_q, 4=W_k, 5=W_v, 6=gamma
    const float* e     = (const float*)d_in[1];
    const float* p     = (const float*)d_in[2];
    const float* Wq    = (const float*)d_in[3];
    const float* Wk    = (const float*)d_in[4];
    const float* Wv    = (const float*)d_in[5];
    const float* gamma = (const float*)d_in[6];

    const size_t NROW = (size_t)BSR * DD;   // 1048576 elements
    bf16_t* WFq_h = (bf16_t*)d_ws;          // fragment-major weights
    bf16_t* WFq_l = WFq_h + DD * DD;
    bf16_t* WFk_h = WFq_l + DD * DD;
    bf16_t* WFk_l = WFk_h + DD * DD;
    bf16_t* WFv   = WFk_l + DD * DD;
    float*  q2    = (float*)(WFv + DD * DD);
    float*  k2    = q2 + BSR;
    bf16_t* QFh   = (bf16_t*)(k2 + BSR);    // fragment-major Q/K/V
    bf16_t* QFl   = QFh + NROW;
    bf16_t* KFh   = QFl + NROW;
    bf16_t* KFl   = KFh + NROW;
    bf16_t* VF    = KFl + NROW;
    float*  part  = (float*)(VF + NROW);    // 3 x B x H x S x D f32 (~101MB)

    float* out = (float*)d_out;

    att_wtrans<<<dim3(49), dim3(256), 0, stream>>>(
        Wq, Wk, Wv, WFq_h, WFq_l, WFk_h, WFk_l, WFv, q2, k2);

    att_gemm_qkv<<<dim3((BSR / 16) * 4), dim3(256), 0, stream>>>(
        p, e, WFq_h, WFq_l, WFk_h, WFk_l, WFv, QFh, QFl, KFh, KFl, VF, q2, k2);

    att_flash<<<dim3(32 * 2 * TSPLIT * BB), dim3(256), 0, stream>>>(
        QFh, QFl, KFh, KFl, VF, q2, k2, gamma, part, out);

    att_reduce_bcast<<<dim3(SS * DD / 4 / 256, BB), dim3(256), 0, stream>>>(
        gamma, part, out);
}

// Round 10
// 127.008 us; speedup vs baseline: 1.0810x; 1.0810x over previous
//
#include <hip/hip_runtime.h>
#include <hip/hip_bf16.h>

// Problem: B=2, S=2048, D=256, H=8.
// out[b,h,s,:] = sum_{t<=s} exp( max(d2(s,t),0) / (2*gamma_h - 1e-6) ) * V[b,t,:]
// d2(s,t) = |Q_s|^2 + |K_t|^2 - 2 Q_s.K_t ; Q=p@Wq, K=p@Wk, V=e@Wv.
// Heads with equal gamma produce identical outputs -> dedupe by representative.
//
// R7: fragment-major operands (1KB contiguous b128 runs).  R8: split partials
// + reduce (136us).  R9 TSPLIT=8 / R10 fence-fusion / R12 / R13: regressed,
// reverted.  R11: dual-tile flash ILP (131.8).  R14: gemm bounds(256,3) +
// XCD-local p/e decode: 128.0us (best).  R15: half-split grid broke flash's
// triangle-pair load balance -> reverted.
// R16: software-pipeline flash: steady-state iteration = scores(group j)
// || PV(group j-1) in ONE basic block (Pb double-buffered).  R17 == R16
// resubmitted: R9's bench failed at container acquisition (infra), no
// measurement was taken.  Kernel re-audited: barriers block-uniform, no
// fences, vf WAR is in-thread -> no hang path found.

#define BB   2
#define SS   2048
#define DD   256
#define HH   8
#define BSR  (BB*SS)        // 4096 rows
#define TSPLIT 4

typedef __bf16 bf16_t;
typedef __bf16 bf16x8 __attribute__((ext_vector_type(8)));
typedef float  f32x4  __attribute__((ext_vector_type(4)));

static __device__ __forceinline__ f32x4 mfma16(bf16x8 a, bf16x8 b, f32x4 c) {
    return __builtin_amdgcn_mfma_f32_16x16x32_bf16(a, b, c, 0, 0, 0);
}

// ---------------------------------------------------------------------------
// K0: W -> fragment-major WF (hi/lo split), plus q2/k2 zeroing (block 48).
// WF chunk (g16 in [0,16), kc in [0,8)) holds 512 elems at ((g16*8+kc)*512):
// position u*8+j = W^T[n = g16*16 + (u&15)][k = kc*32 + (u>>4)*8 + j].
// gemm's B-frag load is then base + lane*8 : contiguous 1KB per wave.
// ---------------------------------------------------------------------------
__global__ __launch_bounds__(256) void att_wtrans(
    const float* __restrict__ Wq, const float* __restrict__ Wk,
    const float* __restrict__ Wv,
    bf16_t* __restrict__ WFq_h, bf16_t* __restrict__ WFq_l,
    bf16_t* __restrict__ WFk_h, bf16_t* __restrict__ WFk_l,
    bf16_t* __restrict__ WFv, float* __restrict__ q2, float* __restrict__ k2)
{
    __shared__ float tT[64][68];    // [n_local][k_local], pad 68
    const int tid = threadIdx.x;
    if (blockIdx.x == 48) {         // zero q2/k2 (gemm accumulates atomically)
        for (int i = tid; i < BSR; i += 256) { q2[i] = 0.f; k2[i] = 0.f; }
        return;
    }
    const int mat = blockIdx.x >> 4;        // 0=Wq 1=Wk 2=Wv
    const int tl  = blockIdx.x & 15;
    const int tr  = (tl >> 2) * 64, tc = (tl & 3) * 64;  // k-range, n-range
    const float* W = (mat == 0) ? Wq : ((mat == 1) ? Wk : Wv);

    // load W[k][n] tile rows coalesced, scatter transposed into LDS
#pragma unroll
    for (int i = 0; i < 4; ++i) {
        const int fidx = i * 256 + tid;     // [0,1024) float4 units
        const int r  = fidx >> 4;           // k_local
        const int c4 = fidx & 15;           // n_local/4
        const float4 v = *(const float4*)(W + (size_t)(tr + r) * DD + tc + c4 * 4);
        tT[c4 * 4 + 0][r] = v.x; tT[c4 * 4 + 1][r] = v.y;
        tT[c4 * 4 + 2][r] = v.z; tT[c4 * 4 + 3][r] = v.w;
    }
    __syncthreads();

#pragma unroll
    for (int i = 0; i < 2; ++i) {
        const int uidx  = i * 256 + tid;    // [0,512) 16B units
        const int chunk = uidx >> 6;        // kc_l(2) x c16(4)
        const int kc_l  = chunk >> 2, c16 = chunk & 3;
        const int u = uidx & 63, m16 = u & 15, quad = u >> 4;
        const float* src = &tT[c16 * 16 + m16][kc_l * 32 + quad * 8];
        const float4 a = *(const float4*)src;
        const float4 bq = *(const float4*)(src + 4);
        const float f[8] = {a.x, a.y, a.z, a.w, bq.x, bq.y, bq.z, bq.w};
        bf16x8 hi, lo;
#pragma unroll
        for (int j = 0; j < 8; ++j) {
            const bf16_t h = (bf16_t)f[j];
            hi[j] = h; lo[j] = (bf16_t)(f[j] - (float)h);
        }
        const int g16 = (tc >> 4) + c16;
        const int kcg = (tr >> 5) + kc_l;
        const size_t off = ((size_t)(g16 * 8 + kcg)) * 512 + (size_t)u * 8;
        if (mat == 0)      { *(bf16x8*)(WFq_h + off) = hi; *(bf16x8*)(WFq_l + off) = lo; }
        else if (mat == 1) { *(bf16x8*)(WFk_h + off) = hi; *(bf16x8*)(WFk_l + off) = lo; }
        else               { *(bf16x8*)(WFv + off)  = hi; }
    }
}

// ---------------------------------------------------------------------------
// K1: fused QKV projection via MFMA + DIRECT fragment-major epilogue.
// Block = 256 thr, 16 rows x 64 n-cols.  R14: bounds(256,3) for 3 blocks/CU
// TLP; bijective XCD-local decode: xcd=bid&7, j=bid>>3, nb=j>>5,
// rowslice=xcd*32+(j&31) -> all 4 nb-jobs of a row-slice share one XCD's L2.
// ---------------------------------------------------------------------------
__global__ __launch_bounds__(256, 3) void att_gemm_qkv(
    const float* __restrict__ p, const float* __restrict__ e,
    const bf16_t* __restrict__ WFq_h, const bf16_t* __restrict__ WFq_l,
    const bf16_t* __restrict__ WFk_h, const bf16_t* __restrict__ WFk_l,
    const bf16_t* __restrict__ WFv,
    bf16_t* __restrict__ QFh, bf16_t* __restrict__ QFl,
    bf16_t* __restrict__ KFh, bf16_t* __restrict__ KFl,
    bf16_t* __restrict__ VF, float* __restrict__ q2, float* __restrict__ k2)
{
    __shared__ float pL[16][264];
    __shared__ float eL[16][264];
    __shared__ float fQ[16][68];
    __shared__ float fK[16][68];
    __shared__ float fV[16][68];

    const int tid  = threadIdx.x;
    const int w    = tid >> 6;
    const int lane = tid & 63;
    const int m16  = lane & 15;
    const int quad = lane >> 4;
    const int xcd  = blockIdx.x & 7;
    const int jid  = blockIdx.x >> 3;      // [0,128)
    const int nb   = jid >> 5;             // [0,4)
    const int row0 = (xcd * 32 + (jid & 31)) * 16;

    // stage p/e tiles (16 rows x 256 cols), coalesced
#pragma unroll
    for (int i = 0; i < 4; ++i) {
        const int fidx = i * 256 + tid;     // [0,1024) float4
        const int r  = fidx >> 6;
        const int c4 = fidx & 63;
        const float4 pv = *(const float4*)(p + (size_t)(row0 + r) * DD + c4 * 4);
        const float4 ev = *(const float4*)(e + (size_t)(row0 + r) * DD + c4 * 4);
        *(float4*)&pL[r][c4 * 4] = pv;
        *(float4*)&eL[r][c4 * 4] = ev;
    }
    __syncthreads();

    f32x4 aQ = f32x4{0.f, 0.f, 0.f, 0.f};
    f32x4 aK = f32x4{0.f, 0.f, 0.f, 0.f};
    f32x4 aV = f32x4{0.f, 0.f, 0.f, 0.f};

#pragma unroll 2
    for (int kc = 0; kc < 8; ++kc) {
        const float* ps = &pL[m16][kc * 32 + quad * 8];
        const float* es = &eL[m16][kc * 32 + quad * 8];
        const float4 p0 = *(const float4*)ps;
        const float4 p1 = *(const float4*)(ps + 4);
        const float4 e0 = *(const float4*)es;
        const float4 e1 = *(const float4*)(es + 4);
        const float pa[8] = {p0.x, p0.y, p0.z, p0.w, p1.x, p1.y, p1.z, p1.w};
        const float ea[8] = {e0.x, e0.y, e0.z, e0.w, e1.x, e1.y, e1.z, e1.w};
        bf16x8 aph, apl, aeb;
#pragma unroll
        for (int j = 0; j < 8; ++j) {
            const bf16_t h = (bf16_t)pa[j];
            aph[j] = h;
            apl[j] = (bf16_t)(pa[j] - (float)h);
            aeb[j] = (bf16_t)ea[j];
        }
        const size_t wo = ((size_t)((nb * 4 + w) * 8 + kc)) * 512 + (size_t)lane * 8;
        const bf16x8 bqh = *(const bf16x8*)(WFq_h + wo);
        const bf16x8 bql = *(const bf16x8*)(WFq_l + wo);
        const bf16x8 bkh = *(const bf16x8*)(WFk_h + wo);
        const bf16x8 bkl = *(const bf16x8*)(WFk_l + wo);
        const bf16x8 bv  = *(const bf16x8*)(WFv + wo);
        aQ = mfma16(aph, bqh, aQ);
        aQ = mfma16(apl, bqh, aQ);
        aQ = mfma16(aph, bql, aQ);
        aK = mfma16(aph, bkh, aK);
        aK = mfma16(apl, bkh, aK);
        aK = mfma16(aph, bkl, aK);
        aV = mfma16(aeb, bv, aV);
    }

    // stage accumulators f32 into LDS for the fragment transpose
#pragma unroll
    for (int r = 0; r < 4; ++r) {
        const int rl = quad * 4 + r;          // C/D row = quad*4+reg
        fQ[rl][w * 16 + m16] = aQ[r];
        fK[rl][w * 16 + m16] = aK[r];
        fV[rl][w * 16 + m16] = aV[r];
    }

    // q2/k2 row-norm partials (from f32 accumulators)
#pragma unroll
    for (int r = 0; r < 4; ++r) {
        float vq = aQ[r] * aQ[r], vk = aK[r] * aK[r];
#pragma unroll
        for (int off = 8; off >= 1; off >>= 1) {
            vq += __shfl_xor(vq, off);
            vk += __shfl_xor(vk, off);
        }
        if (m16 == 0) {
            atomicAdd(q2 + row0 + quad * 4 + r, vq);
            atomicAdd(k2 + row0 + quad * 4 + r, vk);
        }
    }

    __syncthreads();

    const int b   = row0 >> 11;
    const int sl  = row0 & 2047;
    const int tt  = sl >> 6;
    const int st  = sl >> 5;
    const int w4  = (sl >> 4) & 3;   // KF row-group
    const int mt  = (sl >> 4) & 1;   // QF row-group
    const int kc2 = (sl >> 5) & 1;   // VF t-half
    const int uh  = (sl >> 4) & 1;   // VF u-half

    if (w < 2) {
        // QF chunk kc = nb*2 + w  (hi + lo)
        const int cl = w;
        const float* src = &fQ[m16][cl * 32 + quad * 8];
        const float4 a = *(const float4*)src;
        const float4 c = *(const float4*)(src + 4);
        const float f[8] = {a.x, a.y, a.z, a.w, c.x, c.y, c.z, c.w};
        bf16x8 hi, lo;
#pragma unroll
        for (int j = 0; j < 8; ++j) {
            const bf16_t h = (bf16_t)f[j];
            hi[j] = h; lo[j] = (bf16_t)(f[j] - (float)h);
        }
        const size_t off = ((size_t)(b * 64 + st)) * 8192
                         + (size_t)(mt * 8 + nb * 2 + cl) * 512 + (size_t)lane * 8;
        *(bf16x8*)(QFh + off) = hi; *(bf16x8*)(QFl + off) = lo;
    } else {
        // KF chunk kc = nb*2 + (w-2)  (hi + lo)
        const int cl = w - 2;
        const float* src = &fK[m16][cl * 32 + quad * 8];
        const float4 a = *(const float4*)src;
        const float4 c = *(const float4*)(src + 4);
        const float f[8] = {a.x, a.y, a.z, a.w, c.x, c.y, c.z, c.w};
        bf16x8 hi, lo;
#pragma unroll
        for (int j = 0; j < 8; ++j) {
            const bf16_t h = (bf16_t)f[j];
            hi[j] = h; lo[j] = (bf16_t)(f[j] - (float)h);
        }
        const size_t off = ((size_t)(b * 32 + tt)) * 16384
                         + (size_t)(w4 * 8 + nb * 2 + cl) * 512 + (size_t)lane * 8;
        *(bf16x8*)(KFh + off) = hi; *(bf16x8*)(KFl + off) = lo;
    }

    // VF half-chunks: wave w handles nt=w with lanes 0..31 (u-half uh)
    if (lane < 32) {
        const int nt  = w;
        const int u   = uh * 32 + lane;
        const int tl0 = (lane >> 4) * 8;     // t_local base within block rows
        bf16x8 vb;
#pragma unroll
        for (int j = 0; j < 8; ++j)
            vb[j] = (bf16_t)fV[tl0 + j][nt * 16 + (lane & 15)];
        const size_t off = ((size_t)(b * 32 + tt)) * 16384
                         + (size_t)(nb * 8 + kc2 * 4 + nt) * 512 + (size_t)u * 8;
        *(bf16x8*)(VF + off) = vb;
    }
}

// ---------------------------------------------------------------------------
// K2: flash-style causal pass, triangle-paired, fragment-major operands.
// Grid = 256 blocks (32 pairs x 4 splits x 2 b), bid&7 == split*2+b so each
// XCD hosts one (split,b) class (K/V set fits its 4MiB L2).
// R16: software-pipelined.  Steady state (one basic block, branch-free):
//   scores(group j) -> Pb[q]  ||  PV(group j-1) from Pb[q^1] + vf regs
//   then vf <- V(group j); barrier; q^=1.
// PV's 8 independent O accs + V loads give the scheduler independent work
// to interleave with the 4 score chains and exp VALU.  Same barrier count,
// same O add order as R11/R14 -> bit-identical output.
// ---------------------------------------------------------------------------
__global__ __launch_bounds__(256, 1) void att_flash(
    const bf16_t* __restrict__ QFh, const bf16_t* __restrict__ QFl,
    const bf16_t* __restrict__ KFh, const bf16_t* __restrict__ KFl,
    const bf16_t* __restrict__ VF, const float* __restrict__ q2,
    const float* __restrict__ k2, const float* __restrict__ gamma,
    float* __restrict__ part, float* __restrict__ out)
{
    __shared__ bf16_t Pb[2][2][32][72];   // [parity][tile-in-group][s][t]

    const int tid   = threadIdx.x;
    const int pair  = blockIdx.x >> 3;     // 0..31
    const int sub   = blockIdx.x & 7;      // == xcd class
    const int split = sub >> 1;            // 0..3
    const int b     = sub & 1;
    const int wave  = tid >> 6;
    const int lane  = tid & 63;
    const int m16   = lane & 15;
    const int quad  = lane >> 4;

    float g[8];
#pragma unroll
    for (int h = 0; h < 8; ++h) g[h] = gamma[h];

    int q = 0;

    for (int half = 0; half < 2; ++half) {
        const int st = half ? (63 - pair) : pair;
        const int s0 = st * 32;

        // Q fragments -> registers, contiguous chunk loads.
        bf16x8 aQh[2][8], aQl[2][8];
        const size_t qtile = ((size_t)(b * 64 + st)) * 8192 + (size_t)lane * 8;
#pragma unroll
        for (int mt = 0; mt < 2; ++mt)
#pragma unroll
            for (int kc = 0; kc < 8; ++kc) {
                const size_t base = qtile + (size_t)(mt * 8 + kc) * 512;
                aQh[mt][kc] = *(const bf16x8*)(QFh + base);
                aQl[mt][kc] = *(const bf16x8*)(QFl + base);
            }

        float q2r[2][4];
#pragma unroll
        for (int mt = 0; mt < 2; ++mt)
#pragma unroll
            for (int r = 0; r < 4; ++r)
                q2r[mt][r] = q2[b * SS + s0 + mt * 16 + quad * 4 + r];

        const int n_tiles = (s0 + 31) / 64 + 1;

        for (int h = 0; h < HH; ++h) {
            int rep = 0;
            while (g[rep] != g[h]) ++rep;
            if (rep != h) continue;
            const float cexp = 1.0f / (2.0f * g[h] - 1e-6f);

            f32x4 O[2][4];
#pragma unroll
            for (int mt = 0; mt < 2; ++mt)
#pragma unroll
                for (int nt = 0; nt < 4; ++nt)
                    O[mt][nt] = f32x4{0.f, 0.f, 0.f, 0.f};

            bf16x8 vf[2][2][4];   // pending group's V [tile][kc2][nt]

            // --- helpers (inlined; constant slot args propagate) ---
            auto SCORES_DUAL = [&](int tiA, int tiB) {
                const int tgA = tiA * 64 + wave * 16 + m16;
                const int tgB = tiB * 64 + wave * 16 + m16;
                const size_t tileA = ((size_t)(b * 32 + tiA)) * 16384
                                   + (size_t)wave * 4096 + (size_t)lane * 8;
                const size_t tileB = ((size_t)(b * 32 + tiB)) * 16384
                                   + (size_t)wave * 4096 + (size_t)lane * 8;
                const float k2A = k2[b * SS + tgA];
                const float k2B = k2[b * SS + tgB];
                f32x4 aA0 = f32x4{0.f, 0.f, 0.f, 0.f};
                f32x4 aA1 = f32x4{0.f, 0.f, 0.f, 0.f};
                f32x4 aB0 = f32x4{0.f, 0.f, 0.f, 0.f};
                f32x4 aB1 = f32x4{0.f, 0.f, 0.f, 0.f};
#pragma unroll
                for (int kc = 0; kc < 8; ++kc) {
                    const bf16x8 bhA = *(const bf16x8*)(KFh + tileA + (size_t)kc * 512);
                    const bf16x8 blA = *(const bf16x8*)(KFl + tileA + (size_t)kc * 512);
                    const bf16x8 bhB = *(const bf16x8*)(KFh + tileB + (size_t)kc * 512);
                    const bf16x8 blB = *(const bf16x8*)(KFl + tileB + (size_t)kc * 512);
                    aA0 = mfma16(aQh[0][kc], bhA, aA0);
                    aA1 = mfma16(aQh[1][kc], bhA, aA1);
                    aB0 = mfma16(aQh[0][kc], bhB, aB0);
                    aB1 = mfma16(aQh[1][kc], bhB, aB1);
                    aA0 = mfma16(aQl[0][kc], bhA, aA0);
                    aA1 = mfma16(aQl[1][kc], bhA, aA1);
                    aB0 = mfma16(aQl[0][kc], bhB, aB0);
                    aB1 = mfma16(aQl[1][kc], bhB, aB1);
                    aA0 = mfma16(aQh[0][kc], blA, aA0);
                    aA1 = mfma16(aQh[1][kc], blA, aA1);
                    aB0 = mfma16(aQh[0][kc], blB, aB0);
                    aB1 = mfma16(aQh[1][kc], blB, aB1);
                }
#pragma unroll
                for (int mt = 0; mt < 2; ++mt) {
#pragma unroll
                    for (int r = 0; r < 4; ++r) {
                        const int sl = mt * 16 + quad * 4 + r;
                        const int sg = s0 + sl;
                        float dA = q2r[mt][r] + k2A - 2.0f * (mt ? aA1[r] : aA0[r]);
                        dA = fmaxf(dA, 0.0f);
                        Pb[q][0][sl][wave * 16 + m16] =
                            (bf16_t)((tgA <= sg) ? __expf(cexp * dA) : 0.0f);
                        float dB = q2r[mt][r] + k2B - 2.0f * (mt ? aB1[r] : aB0[r]);
                        dB = fmaxf(dB, 0.0f);
                        Pb[q][1][sl][wave * 16 + m16] =
                            (bf16_t)((tgB <= sg) ? __expf(cexp * dB) : 0.0f);
                    }
                }
            };

            auto SCORES_SINGLE = [&](int tiA) {
                const int tg = tiA * 64 + wave * 16 + m16;
                const size_t tile = ((size_t)(b * 32 + tiA)) * 16384
                                  + (size_t)wave * 4096 + (size_t)lane * 8;
                const float k2v = k2[b * SS + tg];
                f32x4 acc0 = f32x4{0.f, 0.f, 0.f, 0.f};
                f32x4 acc1 = f32x4{0.f, 0.f, 0.f, 0.f};
#pragma unroll
                for (int kc = 0; kc < 8; ++kc) {
                    const bf16x8 bh = *(const bf16x8*)(KFh + tile + (size_t)kc * 512);
                    const bf16x8 bl = *(const bf16x8*)(KFl + tile + (size_t)kc * 512);
                    acc0 = mfma16(aQh[0][kc], bh, acc0);
                    acc1 = mfma16(aQh[1][kc], bh, acc1);
                    acc0 = mfma16(aQl[0][kc], bh, acc0);
                    acc1 = mfma16(aQl[1][kc], bh, acc1);
                    acc0 = mfma16(aQh[0][kc], bl, acc0);
                    acc1 = mfma16(aQh[1][kc], bl, acc1);
                }
#pragma unroll
                for (int mt = 0; mt < 2; ++mt) {
#pragma unroll
                    for (int r = 0; r < 4; ++r) {
                        const int sl = mt * 16 + quad * 4 + r;
                        const int sg = s0 + sl;
                        float d2 = q2r[mt][r] + k2v - 2.0f * (mt ? acc1[r] : acc0[r]);
                        d2 = fmaxf(d2, 0.0f);
                        Pb[q][0][sl][wave * 16 + m16] =
                            (bf16_t)((tg <= sg) ? __expf(cexp * d2) : 0.0f);
                    }
                }
            };

            auto PV_ONE = [&](int slot) {    // always called with constant slot
#pragma unroll
                for (int kc2 = 0; kc2 < 2; ++kc2) {
                    const bf16x8 pa0 = *(const bf16x8*)
                        &Pb[q ^ 1][slot][m16][kc2 * 32 + quad * 8];
                    const bf16x8 pa1 = *(const bf16x8*)
                        &Pb[q ^ 1][slot][m16 + 16][kc2 * 32 + quad * 8];
#pragma unroll
                    for (int nt = 0; nt < 4; ++nt) {
                        O[0][nt] = mfma16(pa0, vf[slot][kc2][nt], O[0][nt]);
                        O[1][nt] = mfma16(pa1, vf[slot][kc2][nt], O[1][nt]);
                    }
                }
            };

            auto LOADV = [&](int slot, int tiX) {   // constant slot
                const size_t tile = ((size_t)(b * 32 + tiX)) * 16384
                                  + (size_t)wave * 4096 + (size_t)lane * 8;
#pragma unroll
                for (int kc2 = 0; kc2 < 2; ++kc2)
#pragma unroll
                    for (int nt = 0; nt < 4; ++nt)
                        vf[slot][kc2][nt] = *(const bf16x8*)(
                            VF + tile + (size_t)(kc2 * 4 + nt) * 512);
            };

            int ti = split;
            bool pendDual = false;

            if (ti < n_tiles) {
                // ---- prologue: first group, no pending PV ----
                const bool dual0 = (ti + TSPLIT < n_tiles);
                if (dual0) {
                    SCORES_DUAL(ti, ti + TSPLIT);
                    LOADV(0, ti); LOADV(1, ti + TSPLIT);
                } else {
                    SCORES_SINGLE(ti);
                    LOADV(0, ti);
                }
                __syncthreads();
                q ^= 1;
                pendDual = dual0;
                ti += dual0 ? 2 * TSPLIT : TSPLIT;

                // ---- steady state: dual scores || dual PV, one BB ----
                while (ti + TSPLIT < n_tiles) {
                    SCORES_DUAL(ti, ti + TSPLIT);
                    PV_ONE(0); PV_ONE(1);
                    LOADV(0, ti); LOADV(1, ti + TSPLIT);
                    __syncthreads();
                    q ^= 1;
                    ti += 2 * TSPLIT;
                }

                // ---- optional final single group (pending is dual here) ----
                if (ti < n_tiles) {
                    SCORES_SINGLE(ti);
                    PV_ONE(0); PV_ONE(1);
                    LOADV(0, ti);
                    __syncthreads();
                    q ^= 1;
                    pendDual = false;
                    ti += TSPLIT;
                }

                // ---- drain pending PV ----
                PV_ONE(0);
                if (pendDual) PV_ONE(1);
            }

            // plain stores: split0 -> out slab, splits 1..3 -> ws partials
            float* dst = (split == 0)
                ? out  + (((size_t)b * HH + h) * SS + s0) * DD
                : part + ((((size_t)(split - 1) * BB + b) * HH + h) * SS + s0) * DD;
#pragma unroll
            for (int mt = 0; mt < 2; ++mt)
#pragma unroll
                for (int nt = 0; nt < 4; ++nt)
#pragma unroll
                    for (int r = 0; r < 4; ++r)
                        dst[(size_t)(mt * 16 + quad * 4 + r) * DD
                            + wave * 64 + nt * 16 + m16] = O[mt][nt][r];
        }
    }
}

// ---------------------------------------------------------------------------
// K3: reduce split partials into rep heads and broadcast to duplicate-gamma
// heads.  out[b][rep] already holds split0; add 3 partial slabs, write to
// every head sharing that gamma.
// ---------------------------------------------------------------------------
__global__ __launch_bounds__(256) void att_reduce_bcast(
    const float* __restrict__ gamma, const float* __restrict__ part,
    float* __restrict__ out)
{
    const int j = blockIdx.x * 256 + threadIdx.x;   // float4 index within slab
    const int b = blockIdx.y;
    const int slab = SS * DD / 4;

    float g[8];
#pragma unroll
    for (int h = 0; h < 8; ++h) g[h] = gamma[h];

    const float4* pp = (const float4*)part;
    float4* o4 = (float4*)out;

    float4 repval{0.f, 0.f, 0.f, 0.f};
    int last_rep = -1;
#pragma unroll
    for (int h = 0; h < HH; ++h) {
        int rep = 0;
        while (g[rep] != g[h]) ++rep;
        float4* o = o4 + ((size_t)(b * HH + h)) * slab + j;
        if (rep == h) {
            float4 v = *o;
#pragma unroll
            for (int k = 0; k < TSPLIT - 1; ++k) {
                const float4 pv = pp[(((size_t)k * BB + b) * HH + h) * slab + j];
                v.x += pv.x; v.y += pv.y; v.z += pv.z; v.w += pv.w;
            }
            *o = v; repval = v; last_rep = h;
        } else {
            if (last_rep != rep) {
                repval = o4[((size_t)(b * HH + rep)) * slab + j];
                last_rep = rep;
            }
            *o = repval;
        }
    }
}

extern "C" void kernel_launch(void* const* d_in, const int* in_sizes, int n_in,
                              void* d_out, int out_size, void* d_ws, size_t ws_size,
                              hipStream_t stream) {
    (void)in_sizes; (void)n_in; (void)out_size; (void)ws_size;
    // inputs: 0=x (unused), 1=e, 2=p, 3=W_q, 4=W_k, 5=W_v, 6=gamma
    const float* e     = (const float*)d_in[1];
    const float* p     = (const float*)d_in[2];
    const float* Wq    = (const float*)d_in[3];
    const float* Wk    = (const float*)d_in[4];
    const float* Wv    = (const float*)d_in[5];
    const float* gamma = (const float*)d_in[6];

    const size_t NROW = (size_t)BSR * DD;   // 1048576 elements
    bf16_t* WFq_h = (bf16_t*)d_ws;          // fragment-major weights
    bf16_t* WFq_l = WFq_h + DD * DD;
    bf16_t* WFk_h = WFq_l + DD * DD;
    bf16_t* WFk_l = WFk_h + DD * DD;
    bf16_t* WFv   = WFk_l + DD * DD;
    float*  q2    = (float*)(WFv + DD * DD);
    float*  k2    = q2 + BSR;
    bf16_t* QFh   = (bf16_t*)(k2 + BSR);    // fragment-major Q/K/V
    bf16_t* QFl   = QFh + NROW;
    bf16_t* KFh   = QFl + NROW;
    bf16_t* KFl   = KFh + NROW;
    bf16_t* VF    = KFl + NROW;
    float*  part  = (float*)(VF + NROW);    // 3 x B x H x S x D f32 (~101MB)

    float* out = (float*)d_out;

    att_wtrans<<<dim3(49), dim3(256), 0, stream>>>(
        Wq, Wk, Wv, WFq_h, WFq_l, WFk_h, WFk_l, WFv, q2, k2);

    att_gemm_qkv<<<dim3((BSR / 16) * 4), dim3(256), 0, stream>>>(
        p, e, WFq_h, WFq_l, WFk_h, WFk_l, WFv, QFh, QFl, KFh, KFl, VF, q2, k2);

    att_flash<<<dim3(32 * TSPLIT * BB), dim3(256), 0, stream>>>(
        QFh, QFl, KFh, KFl, VF, q2, k2, gamma, part, out);

    att_reduce_bcast<<<dim3(SS * DD / 4 / 256, BB), dim3(256), 0, stream>>>(
        gamma, part, out);
}